// Round 1
// baseline (569.011 us; speedup 1.0000x reference)
//
#include <hip/hip_runtime.h>
#include <stdint.h>
#include <stddef.h>

// DecoderMHA: x[4,2048,1024] fp32 -> out fp32 [4,2048,1024]
// Pipeline: cvt(fp32->bf16) -> QKV gemm (bf16 MFMA) -> flash attention -> out proj.
// Workspace layout (92.3 MB total): Xb | Wqb Wkb Wvb Wob | Qb Kb Vb | Ob

typedef __bf16 bf16;
typedef __bf16 bf16x8 __attribute__((ext_vector_type(8)));
typedef float f32x4 __attribute__((ext_vector_type(4)));

#define DM   1024
#define NH   16
#define DK   64
#define BSZ  4
#define SEQL 2048
#define NTOK 8192   // BSZ*SEQL

__device__ __forceinline__ void async16(const bf16* g, bf16* l) {
  __builtin_amdgcn_global_load_lds(
      (__attribute__((address_space(1))) void*)g,
      (__attribute__((address_space(3))) void*)l, 16, 0, 0);
}

// ---------------- fp32 -> bf16 converts ----------------
__global__ __launch_bounds__(256) void cvt_x_kernel(const float* __restrict__ s,
                                                    bf16* __restrict__ d) {
  int i = (blockIdx.x * 256 + threadIdx.x) * 8;
  float4 v0 = *(const float4*)(s + i);
  float4 v1 = *(const float4*)(s + i + 4);
  bf16x8 o = {(bf16)v0.x, (bf16)v0.y, (bf16)v0.z, (bf16)v0.w,
              (bf16)v1.x, (bf16)v1.y, (bf16)v1.z, (bf16)v1.w};
  *(bf16x8*)(d + i) = o;
}

__global__ __launch_bounds__(256) void cvt_w_kernel(
    const float* __restrict__ w0, const float* __restrict__ w1,
    const float* __restrict__ w2, const float* __restrict__ w3,
    bf16* __restrict__ d0, bf16* __restrict__ d1,
    bf16* __restrict__ d2, bf16* __restrict__ d3) {
  const float* s; bf16* d;
  switch (blockIdx.y) {
    case 0:  s = w0; d = d0; break;
    case 1:  s = w1; d = d1; break;
    case 2:  s = w2; d = d2; break;
    default: s = w3; d = d3; break;
  }
  int i = (blockIdx.x * 256 + threadIdx.x) * 8;
  float4 v0 = *(const float4*)(s + i);
  float4 v1 = *(const float4*)(s + i + 4);
  bf16x8 o = {(bf16)v0.x, (bf16)v0.y, (bf16)v0.z, (bf16)v0.w,
              (bf16)v1.x, (bf16)v1.y, (bf16)v1.z, (bf16)v1.w};
  *(bf16x8*)(d + i) = o;
}

// ---------------- 128x128 bf16 GEMM body (C = A @ W^T + bias) ----------------
// A: [M,1024] bf16 row-major, W: [1024,1024] bf16 row-major ([out_ch, in_ch]).
// OUT_MODE 0: bf16 out in head-split layout [B,H,S,dk]
// OUT_MODE 1: fp32 out flat [M, 1024]
template <int OUT_MODE>
__device__ __forceinline__ void gemm128(const bf16* __restrict__ A,
                                        const bf16* __restrict__ W,
                                        const float* __restrict__ bias,
                                        void* __restrict__ outp) {
  __shared__ bf16 As[128 * 32];
  __shared__ bf16 Bs[128 * 32];
  const int tid  = threadIdx.x;
  const int lane = tid & 63;
  const int wv   = tid >> 6;
  const int wm   = (wv & 1) * 64;
  const int wn   = (wv >> 1) * 64;
  const int c    = lane & 15;
  const int quad = lane >> 4;
  const int bm   = blockIdx.y * 128;
  const int bn   = blockIdx.x * 128;

  f32x4 acc[4][4] = {};

  for (int k0 = 0; k0 < DM; k0 += 32) {
    __syncthreads();
#pragma unroll
    for (int j = 0; j < 2; ++j) {
      int i = j * 256 + tid;  // 16B chunk index; LDS dst = base + i*16 (wave-linear)
      async16(A + (size_t)(bm + (i >> 2)) * DM + k0 + (i & 3) * 8, As + i * 8);
      async16(W + (size_t)(bn + (i >> 2)) * DM + k0 + (i & 3) * 8, Bs + i * 8);
    }
    __syncthreads();
    bf16x8 af[4], bg[4];
#pragma unroll
    for (int mi = 0; mi < 4; ++mi)
      af[mi] = *(const bf16x8*)&As[(wm + mi * 16 + c) * 32 + quad * 8];
#pragma unroll
    for (int ni = 0; ni < 4; ++ni)
      bg[ni] = *(const bf16x8*)&Bs[(wn + ni * 16 + c) * 32 + quad * 8];
#pragma unroll
    for (int mi = 0; mi < 4; ++mi)
#pragma unroll
      for (int ni = 0; ni < 4; ++ni)
        acc[mi][ni] = __builtin_amdgcn_mfma_f32_16x16x32_bf16(af[mi], bg[ni],
                                                              acc[mi][ni], 0, 0, 0);
  }

  float bias_r[4];
#pragma unroll
  for (int ni = 0; ni < 4; ++ni) bias_r[ni] = bias[bn + wn + ni * 16 + c];

#pragma unroll
  for (int mi = 0; mi < 4; ++mi) {
#pragma unroll
    for (int reg = 0; reg < 4; ++reg) {
      int m_g = bm + wm + mi * 16 + quad * 4 + reg;
#pragma unroll
      for (int ni = 0; ni < 4; ++ni) {
        int n_g = bn + wn + ni * 16 + c;
        float v = acc[mi][ni][reg] + bias_r[ni];
        if (OUT_MODE == 0) {
          int b = m_g >> 11, s = m_g & 2047;
          int h = n_g >> 6, d = n_g & 63;
          ((bf16*)outp)[(((size_t)(b * NH + h) * SEQL + s) << 6) + d] = (bf16)v;
        } else {
          ((float*)outp)[(size_t)m_g * DM + n_g] = v;
        }
      }
    }
  }
}

__global__ __launch_bounds__(256) void qkv_gemm(
    const bf16* __restrict__ X,
    const bf16* __restrict__ Wq, const bf16* __restrict__ Wk, const bf16* __restrict__ Wv,
    const float* __restrict__ bq, const float* __restrict__ bk, const float* __restrict__ bv,
    bf16* __restrict__ Q, bf16* __restrict__ K, bf16* __restrict__ V) {
  const bf16* W; const float* bias; bf16* out;
  if (blockIdx.z == 0)      { W = Wq; bias = bq; out = Q; }
  else if (blockIdx.z == 1) { W = Wk; bias = bk; out = K; }
  else                      { W = Wv; bias = bv; out = V; }
  gemm128<0>(X, W, bias, out);
}

__global__ __launch_bounds__(256) void out_gemm(const bf16* __restrict__ A,
                                                const bf16* __restrict__ W,
                                                const float* __restrict__ bias,
                                                float* __restrict__ out) {
  gemm128<1>(A, W, bias, out);
}

// ---------------- flash attention ----------------
// block = (qt, h, b); 4 waves; wave w owns q-rows w*16..w*16+15 of the 64-row q-tile.
// LDS tiles padded to stride 72 elems (16B-aligned rows, kills 16-way b128 conflicts).
#define LSTR 72

__global__ __launch_bounds__(256) void attn_kernel(
    const bf16* __restrict__ Q, const bf16* __restrict__ K, const bf16* __restrict__ V,
    const int* __restrict__ pad, bf16* __restrict__ O) {
  const int qt = blockIdx.x, h = blockIdx.y, b = blockIdx.z;
  const int tid  = threadIdx.x;
  const int lane = tid & 63;
  const int w    = tid >> 6;
  const int c    = lane & 15;
  const int quad = lane >> 4;

  __shared__ bf16 Qs[64 * LSTR];
  __shared__ bf16 Ks[64 * LSTR];
  __shared__ bf16 Vts[64 * LSTR];  // transposed: [d][s_local]
  __shared__ bf16 Ps[64 * LSTR];

  const size_t headoff = ((size_t)(b * NH + h)) * SEQL * DK;
  const bf16* Qh = Q + headoff;
  const bf16* Kh = K + headoff;
  const bf16* Vh = V + headoff;

  // stage Q tile (64x64)
#pragma unroll
  for (int j = 0; j < 2; ++j) {
    int i = j * 256 + tid;
    int r = i >> 3, col = (i & 7) * 8;
    bf16x8 qf = *(const bf16x8*)(Qh + (((size_t)(qt * 64 + r)) << 6) + col);
    *(bf16x8*)&Qs[r * LSTR + col] = qf;
  }

  float m_r[4], l_r[4];
#pragma unroll
  for (int r = 0; r < 4; ++r) { m_r[r] = -1e30f; l_r[r] = 0.f; }
  f32x4 Oacc[4] = {};

  const float sc = 0.125f * 1.44269504088896340736f;  // 1/sqrt(64) * log2(e)

  for (int kt = 0; kt <= qt; ++kt) {
    __syncthreads();
    // stage K tile (natural) and V tile (transposed)
#pragma unroll
    for (int j = 0; j < 2; ++j) {
      int i = j * 256 + tid;
      int r = i >> 3, col = (i & 7) * 8;
      bf16x8 kf = *(const bf16x8*)(Kh + (((size_t)(kt * 64 + r)) << 6) + col);
      *(bf16x8*)&Ks[r * LSTR + col] = kf;
      bf16x8 vf = *(const bf16x8*)(Vh + (((size_t)(kt * 64 + r)) << 6) + col);
#pragma unroll
      for (int e = 0; e < 8; ++e) Vts[(col + e) * LSTR + r] = vf[e];
    }
    __syncthreads();

    // S = Q K^T  (wave's 16 q-rows x 64 keys)
    f32x4 sf[4] = {};
#pragma unroll
    for (int ks = 0; ks < 2; ++ks) {
      bf16x8 a = *(const bf16x8*)&Qs[(w * 16 + c) * LSTR + ks * 32 + quad * 8];
#pragma unroll
      for (int ni = 0; ni < 4; ++ni) {
        bf16x8 bb = *(const bf16x8*)&Ks[(ni * 16 + c) * LSTR + ks * 32 + quad * 8];
        sf[ni] = __builtin_amdgcn_mfma_f32_16x16x32_bf16(a, bb, sf[ni], 0, 0, 0);
      }
    }

    // scale + causal + pad mask
    int pads[4];
#pragma unroll
    for (int ni = 0; ni < 4; ++ni) pads[ni] = pad[b * SEQL + kt * 64 + ni * 16 + c];
#pragma unroll
    for (int ni = 0; ni < 4; ++ni) {
#pragma unroll
      for (int reg = 0; reg < 4; ++reg) {
        float x = sf[ni][reg] * sc;
        bool masked = (pads[ni] == 1);
        if (kt == qt) masked |= (ni * 16 + c) > (w * 16 + quad * 4 + reg);
        sf[ni][reg] = masked ? -1e30f : x;
      }
    }

    // row max (over 4 n-frags, then across the 16 lanes holding the row)
    float alpha[4];
#pragma unroll
    for (int reg = 0; reg < 4; ++reg) {
      float v = fmaxf(fmaxf(sf[0][reg], sf[1][reg]), fmaxf(sf[2][reg], sf[3][reg]));
      v = fmaxf(v, __shfl_xor(v, 1));
      v = fmaxf(v, __shfl_xor(v, 2));
      v = fmaxf(v, __shfl_xor(v, 4));
      v = fmaxf(v, __shfl_xor(v, 8));
      float mn = fmaxf(m_r[reg], v);
      alpha[reg] = exp2f(m_r[reg] - mn);
      m_r[reg] = mn;
    }

    // P = exp2(s - m); write to Ps (C-layout -> A-layout round trip); row sums
    float rowsum[4] = {0.f, 0.f, 0.f, 0.f};
#pragma unroll
    for (int ni = 0; ni < 4; ++ni) {
#pragma unroll
      for (int reg = 0; reg < 4; ++reg) {
        float p = exp2f(sf[ni][reg] - m_r[reg]);
        Ps[(w * 16 + quad * 4 + reg) * LSTR + ni * 16 + c] = (bf16)p;
        rowsum[reg] += p;
      }
    }
#pragma unroll
    for (int reg = 0; reg < 4; ++reg) {
      float v = rowsum[reg];
      v += __shfl_xor(v, 1);
      v += __shfl_xor(v, 2);
      v += __shfl_xor(v, 4);
      v += __shfl_xor(v, 8);
      l_r[reg] = l_r[reg] * alpha[reg] + v;
    }

    // rescale O accumulator
#pragma unroll
    for (int od = 0; od < 4; ++od)
#pragma unroll
      for (int reg = 0; reg < 4; ++reg) Oacc[od][reg] *= alpha[reg];

    // O += P @ V   (A = Ps rows w*16.., B = Vts)
#pragma unroll
    for (int ks = 0; ks < 2; ++ks) {
      bf16x8 a = *(const bf16x8*)&Ps[(w * 16 + c) * LSTR + ks * 32 + quad * 8];
#pragma unroll
      for (int od = 0; od < 4; ++od) {
        bf16x8 bb = *(const bf16x8*)&Vts[(od * 16 + c) * LSTR + ks * 32 + quad * 8];
        Oacc[od] = __builtin_amdgcn_mfma_f32_16x16x32_bf16(a, bb, Oacc[od], 0, 0, 0);
      }
    }
  }

  // epilogue: O /= l, store bf16 in [B, S, D] with channel = h*64 + d
#pragma unroll
  for (int reg = 0; reg < 4; ++reg) {
    float inv = (l_r[reg] > 0.f) ? 1.0f / l_r[reg] : 0.f;
    int qrow = w * 16 + quad * 4 + reg;
    size_t rowoff = ((size_t)(b * SEQL + qt * 64 + qrow)) * DM + h * DK;
#pragma unroll
    for (int od = 0; od < 4; ++od)
      O[rowoff + od * 16 + c] = (bf16)(Oacc[od][reg] * inv);
  }
}

// ---------------- launch ----------------
extern "C" void kernel_launch(void* const* d_in, const int* in_sizes, int n_in,
                              void* d_out, int out_size, void* d_ws, size_t ws_size,
                              hipStream_t stream) {
  const float* x   = (const float*)d_in[0];
  const int*   pad = (const int*)d_in[1];
  const float* Wq  = (const float*)d_in[2];
  const float* bq  = (const float*)d_in[3];
  const float* Wk  = (const float*)d_in[4];
  const float* bk  = (const float*)d_in[5];
  const float* Wv  = (const float*)d_in[6];
  const float* bv  = (const float*)d_in[7];
  const float* Wo  = (const float*)d_in[8];
  const float* bo  = (const float*)d_in[9];
  float* out = (float*)d_out;

  const size_t SZ_X = (size_t)NTOK * DM * 2;  // 16 MB
  const size_t SZ_W = (size_t)DM * DM * 2;    // 2 MB
  char* ws = (char*)d_ws;
  bf16* Xb  = (bf16*)ws;  ws += SZ_X;
  bf16* Wqb = (bf16*)ws;  ws += SZ_W;
  bf16* Wkb = (bf16*)ws;  ws += SZ_W;
  bf16* Wvb = (bf16*)ws;  ws += SZ_W;
  bf16* Wob = (bf16*)ws;  ws += SZ_W;
  bf16* Qb  = (bf16*)ws;  ws += SZ_X;
  bf16* Kb  = (bf16*)ws;  ws += SZ_X;
  bf16* Vb  = (bf16*)ws;  ws += SZ_X;
  bf16* Ob  = (bf16*)ws;  ws += SZ_X;  // total 92.3 MB

  cvt_x_kernel<<<4096, 256, 0, stream>>>(x, Xb);
  cvt_w_kernel<<<dim3(512, 4), 256, 0, stream>>>(Wq, Wk, Wv, Wo, Wqb, Wkb, Wvb, Wob);
  qkv_gemm<<<dim3(8, 64, 3), 256, 0, stream>>>(Xb, Wqb, Wkb, Wvb, bq, bk, bv, Qb, Kb, Vb);
  attn_kernel<<<dim3(32, 16, 4), 256, 0, stream>>>(Qb, Kb, Vb, pad, Ob);
  out_gemm<<<dim3(8, 64), 256, 0, stream>>>(Ob, Wob, bo, out);
}

// Round 2
// 499.616 us; speedup vs baseline: 1.1389x; 1.1389x over previous
//
#include <hip/hip_runtime.h>
#include <stdint.h>
#include <stddef.h>

// DecoderMHA: x[4,2048,1024] fp32 -> out fp32 [4,2048,1024]
// Pipeline: cvt(fp32->bf16) -> QKV gemm (bf16 MFMA, V written transposed) ->
//           barrier-free per-wave flash attention -> out proj.
// Workspace: Xb | Wqb Wkb Wvb Wob | Qb Kb Vtb | Ob  (~88 MB)

typedef __bf16 bf16;
typedef __bf16 bf16x8 __attribute__((ext_vector_type(8)));
typedef __bf16 bf16x4 __attribute__((ext_vector_type(4)));
typedef float f32x4 __attribute__((ext_vector_type(4)));

#define DM   1024
#define NH   16
#define DK   64
#define BSZ  4
#define SEQL 2048
#define NTOK 8192   // BSZ*SEQL

__device__ __forceinline__ void async16(const bf16* g, bf16* l) {
  __builtin_amdgcn_global_load_lds(
      (__attribute__((address_space(1))) void*)g,
      (__attribute__((address_space(3))) void*)l, 16, 0, 0);
}

// ---------------- fp32 -> bf16 converts ----------------
__global__ __launch_bounds__(256) void cvt_x_kernel(const float* __restrict__ s,
                                                    bf16* __restrict__ d) {
  int i = (blockIdx.x * 256 + threadIdx.x) * 8;
  float4 v0 = *(const float4*)(s + i);
  float4 v1 = *(const float4*)(s + i + 4);
  bf16x8 o = {(bf16)v0.x, (bf16)v0.y, (bf16)v0.z, (bf16)v0.w,
              (bf16)v1.x, (bf16)v1.y, (bf16)v1.z, (bf16)v1.w};
  *(bf16x8*)(d + i) = o;
}

__global__ __launch_bounds__(256) void cvt_w_kernel(
    const float* __restrict__ w0, const float* __restrict__ w1,
    const float* __restrict__ w2, const float* __restrict__ w3,
    bf16* __restrict__ d0, bf16* __restrict__ d1,
    bf16* __restrict__ d2, bf16* __restrict__ d3) {
  const float* s; bf16* d;
  switch (blockIdx.y) {
    case 0:  s = w0; d = d0; break;
    case 1:  s = w1; d = d1; break;
    case 2:  s = w2; d = d2; break;
    default: s = w3; d = d3; break;
  }
  int i = (blockIdx.x * 256 + threadIdx.x) * 8;
  float4 v0 = *(const float4*)(s + i);
  float4 v1 = *(const float4*)(s + i + 4);
  bf16x8 o = {(bf16)v0.x, (bf16)v0.y, (bf16)v0.z, (bf16)v0.w,
              (bf16)v1.x, (bf16)v1.y, (bf16)v1.z, (bf16)v1.w};
  *(bf16x8*)(d + i) = o;
}

// ---------------- 128x128 bf16 GEMM body (C = A @ W^T + bias) ----------------
// A: [M,1024] bf16 row-major, W: [1024,1024] bf16 row-major ([out_ch, in_ch]).
// OUT_MODE 0: bf16 out in head-split layout [B,H,S,dk]
// OUT_MODE 1: fp32 out flat [M, 1024]
// OUT_MODE 2: bf16 out TRANSPOSED head-split [B,H,dk,S]  (for V)
template <int OUT_MODE>
__device__ __forceinline__ void gemm128(const bf16* __restrict__ A,
                                        const bf16* __restrict__ W,
                                        const float* __restrict__ bias,
                                        void* __restrict__ outp) {
  __shared__ bf16 As[128 * 32];
  __shared__ bf16 Bs[128 * 32];
  const int tid  = threadIdx.x;
  const int lane = tid & 63;
  const int wv   = tid >> 6;
  const int wm   = (wv & 1) * 64;
  const int wn   = (wv >> 1) * 64;
  const int c    = lane & 15;
  const int quad = lane >> 4;
  const int bm   = blockIdx.y * 128;
  const int bn   = blockIdx.x * 128;

  f32x4 acc[4][4] = {};

  for (int k0 = 0; k0 < DM; k0 += 32) {
    __syncthreads();
#pragma unroll
    for (int j = 0; j < 2; ++j) {
      int i = j * 256 + tid;  // 16B chunk index; LDS dst = base + i*16 (wave-linear)
      async16(A + (size_t)(bm + (i >> 2)) * DM + k0 + (i & 3) * 8, As + i * 8);
      async16(W + (size_t)(bn + (i >> 2)) * DM + k0 + (i & 3) * 8, Bs + i * 8);
    }
    __syncthreads();
    bf16x8 af[4], bg[4];
#pragma unroll
    for (int mi = 0; mi < 4; ++mi)
      af[mi] = *(const bf16x8*)&As[(wm + mi * 16 + c) * 32 + quad * 8];
#pragma unroll
    for (int ni = 0; ni < 4; ++ni)
      bg[ni] = *(const bf16x8*)&Bs[(wn + ni * 16 + c) * 32 + quad * 8];
#pragma unroll
    for (int mi = 0; mi < 4; ++mi)
#pragma unroll
      for (int ni = 0; ni < 4; ++ni)
        acc[mi][ni] = __builtin_amdgcn_mfma_f32_16x16x32_bf16(af[mi], bg[ni],
                                                              acc[mi][ni], 0, 0, 0);
  }

  float bias_r[4];
#pragma unroll
  for (int ni = 0; ni < 4; ++ni) bias_r[ni] = bias[bn + wn + ni * 16 + c];

  if (OUT_MODE == 2) {
    // V transposed: Vt[((b*NH+h)*DK + d) * SEQL + s]; regs = 4 consecutive s -> b64 store
#pragma unroll
    for (int mi = 0; mi < 4; ++mi) {
      int base = bm + wm + mi * 16 + quad * 4;  // token of reg 0
      int bb = base >> 11, s0 = base & 2047;
#pragma unroll
      for (int ni = 0; ni < 4; ++ni) {
        int n_g = bn + wn + ni * 16 + c;
        int hh = n_g >> 6, dd = n_g & 63;
        bf16x4 pv = {(bf16)(acc[mi][ni][0] + bias_r[ni]),
                     (bf16)(acc[mi][ni][1] + bias_r[ni]),
                     (bf16)(acc[mi][ni][2] + bias_r[ni]),
                     (bf16)(acc[mi][ni][3] + bias_r[ni])};
        *(bf16x4*)&((bf16*)outp)[(((size_t)(bb * NH + hh)) * DK + dd) * SEQL + s0] = pv;
      }
    }
    return;
  }

#pragma unroll
  for (int mi = 0; mi < 4; ++mi) {
#pragma unroll
    for (int reg = 0; reg < 4; ++reg) {
      int m_g = bm + wm + mi * 16 + quad * 4 + reg;
#pragma unroll
      for (int ni = 0; ni < 4; ++ni) {
        int n_g = bn + wn + ni * 16 + c;
        float v = acc[mi][ni][reg] + bias_r[ni];
        if (OUT_MODE == 0) {
          int b = m_g >> 11, s = m_g & 2047;
          int h = n_g >> 6, d = n_g & 63;
          ((bf16*)outp)[(((size_t)(b * NH + h) * SEQL + s) << 6) + d] = (bf16)v;
        } else {
          ((float*)outp)[(size_t)m_g * DM + n_g] = v;
        }
      }
    }
  }
}

__global__ __launch_bounds__(256) void qkv_gemm(
    const bf16* __restrict__ X,
    const bf16* __restrict__ Wq, const bf16* __restrict__ Wk, const bf16* __restrict__ Wv,
    const float* __restrict__ bq, const float* __restrict__ bk, const float* __restrict__ bv,
    bf16* __restrict__ Q, bf16* __restrict__ K, bf16* __restrict__ Vt) {
  if (blockIdx.z == 0)      gemm128<0>(X, Wq, bq, Q);
  else if (blockIdx.z == 1) gemm128<0>(X, Wk, bk, K);
  else                      gemm128<2>(X, Wv, bv, Vt);
}

__global__ __launch_bounds__(256) void out_gemm(const bf16* __restrict__ A,
                                                const bf16* __restrict__ W,
                                                const float* __restrict__ bias,
                                                float* __restrict__ out) {
  gemm128<1>(A, W, bias, out);
}

// ---------------- barrier-free flash attention ----------------
// Block = 4 waves; wave wv owns 32 q-rows (qbase = qblk*128 + wv*32).
// S^T = K·Q^T  (C-layout: col=lane&15=query, row=quad*4+reg=key).
// P transposes to PV A-operand via wave-private LDS (no __syncthreads anywhere).
// PV B-operand = natural b128 rows of pre-transposed Vt.
#define PSTR 40   // LDS row stride in bf16 elems (80 B): b128 reads ~conflict-free

__global__ __launch_bounds__(256) void attn_kernel(
    const bf16* __restrict__ Q, const bf16* __restrict__ K,
    const bf16* __restrict__ Vt, const int* __restrict__ pad,
    bf16* __restrict__ O) {
  const int h = blockIdx.y, b = blockIdx.z;
  const int qblk = gridDim.x - 1 - blockIdx.x;  // big (causal-heavy) blocks first
  const int tid  = threadIdx.x;
  const int lane = tid & 63;
  const int wv   = tid >> 6;
  const int c    = lane & 15;
  const int quad = lane >> 4;
  const int qbase = qblk * 128 + wv * 32;

  __shared__ bf16 Plds_all[4][32 * PSTR];
  bf16* Plds = &Plds_all[wv][0];

  const size_t bh = (size_t)b * NH + h;
  const bf16* Qh  = Q  + bh * SEQL * DK;
  const bf16* Kh  = K  + bh * SEQL * DK;
  const bf16* Vth = Vt + bh * DK * SEQL;
  const int*  padb = pad + b * SEQL;

  // Q fragments (B-operand): lane c = query, k = kh*32 + quad*8 + j
  bf16x8 Qf[2][2];
#pragma unroll
  for (int qf = 0; qf < 2; ++qf)
#pragma unroll
    for (int kh = 0; kh < 2; ++kh)
      Qf[qf][kh] = *(const bf16x8*)&Qh[(size_t)(qbase + qf * 16 + c) * DK + kh * 32 + quad * 8];

  float m_s[2] = {-1e38f, -1e38f};
  float l_s[2] = {0.f, 0.f};
  f32x4 Oc[2][4] = {};
  const float sc = 0.1803368801111204f;  // log2(e) / sqrt(64)
  const int nkt = qbase / 32 + 1;

  for (int kt = 0; kt < nkt; ++kt) {
    const int kb = kt * 32;
    // K fragments (A-operand): lane c = key, k = dk
    bf16x8 Kf[2][2], Vf[4];
#pragma unroll
    for (int kf = 0; kf < 2; ++kf)
#pragma unroll
      for (int kh = 0; kh < 2; ++kh)
        Kf[kf][kh] = *(const bf16x8*)&Kh[(size_t)(kb + kf * 16 + c) * DK + kh * 32 + quad * 8];
    // Vt fragments (PV B-operand): lane c = d (within df tile), k = key = quad*8+j
#pragma unroll
    for (int df = 0; df < 4; ++df)
      Vf[df] = *(const bf16x8*)&Vth[(size_t)(df * 16 + c) * SEQL + kb + quad * 8];
    int4 padv[2];
#pragma unroll
    for (int kf = 0; kf < 2; ++kf)
      padv[kf] = *(const int4*)&padb[kb + kf * 16 + quad * 4];

    // S^T[key][q]
    f32x4 st[2][2] = {};
#pragma unroll
    for (int kh = 0; kh < 2; ++kh)
#pragma unroll
      for (int kf = 0; kf < 2; ++kf)
#pragma unroll
        for (int qf = 0; qf < 2; ++qf)
          st[kf][qf] = __builtin_amdgcn_mfma_f32_16x16x32_bf16(Kf[kf][kh], Qf[qf][kh],
                                                               st[kf][qf], 0, 0, 0);

    // scale + pad mask (+ causal on the diagonal tile only)
    const bool lastt = (kt == nkt - 1);
#pragma unroll
    for (int kf = 0; kf < 2; ++kf) {
      const int* pv = (const int*)&padv[kf];
#pragma unroll
      for (int r = 0; r < 4; ++r) {
        const int key = kb + kf * 16 + quad * 4 + r;
        const bool pm = (pv[r] != 0);
#pragma unroll
        for (int qf = 0; qf < 2; ++qf) {
          float x = st[kf][qf][r] * sc;
          bool msk = pm;
          if (lastt) msk = msk || (key > qbase + qf * 16 + c);
          st[kf][qf][r] = msk ? -3e38f : x;
        }
      }
    }

    // online softmax per q-fragment (reduction over keys = regs + quads)
#pragma unroll
    for (int qf = 0; qf < 2; ++qf) {
      float vmax = -3e38f;
#pragma unroll
      for (int kf = 0; kf < 2; ++kf)
#pragma unroll
        for (int r = 0; r < 4; ++r) vmax = fmaxf(vmax, st[kf][qf][r]);
      vmax = fmaxf(vmax, __shfl_xor(vmax, 16));
      vmax = fmaxf(vmax, __shfl_xor(vmax, 32));
      float mn = fmaxf(m_s[qf], vmax);
      float alpha = __builtin_amdgcn_exp2f(m_s[qf] - mn);
      m_s[qf] = mn;

      float p[8], rs = 0.f;
#pragma unroll
      for (int kf = 0; kf < 2; ++kf)
#pragma unroll
        for (int r = 0; r < 4; ++r) {
          float e = __builtin_amdgcn_exp2f(st[kf][qf][r] - mn);
          p[kf * 4 + r] = e;
          rs += e;
        }
      rs += __shfl_xor(rs, 16);
      rs += __shfl_xor(rs, 32);
      l_s[qf] = l_s[qf] * alpha + rs;

      // P^T regs -> natural P[q][key] rows in wave-private LDS (b64 packed)
      bf16x4 pk0 = {(bf16)p[0], (bf16)p[1], (bf16)p[2], (bf16)p[3]};
      bf16x4 pk1 = {(bf16)p[4], (bf16)p[5], (bf16)p[6], (bf16)p[7]};
      *(bf16x4*)&Plds[(qf * 16 + c) * PSTR + quad * 4] = pk0;
      *(bf16x4*)&Plds[(qf * 16 + c) * PSTR + 16 + quad * 4] = pk1;

      // rescale O (rows are quad*4+reg -> broadcast alpha from lane quad*4+r)
      float ar[4];
#pragma unroll
      for (int r = 0; r < 4; ++r) ar[r] = __shfl(alpha, quad * 4 + r);
#pragma unroll
      for (int df = 0; df < 4; ++df)
#pragma unroll
        for (int r = 0; r < 4; ++r) Oc[qf][df][r] *= ar[r];
    }

    // O += P @ V  (A = P rows from LDS, B = Vt rows; full-rate 16x16x32)
#pragma unroll
    for (int qf = 0; qf < 2; ++qf) {
      bf16x8 af = *(const bf16x8*)&Plds[(qf * 16 + c) * PSTR + quad * 8];
#pragma unroll
      for (int df = 0; df < 4; ++df)
        Oc[qf][df] = __builtin_amdgcn_mfma_f32_16x16x32_bf16(af, Vf[df], Oc[qf][df], 0, 0, 0);
    }
  }

  // epilogue: O /= l; Oc layout col=lane&15=d, row=quad*4+reg=q
#pragma unroll
  for (int qf = 0; qf < 2; ++qf) {
    float linv = (l_s[qf] > 0.f) ? 1.f / l_s[qf] : 0.f;
    float lr[4];
#pragma unroll
    for (int r = 0; r < 4; ++r) lr[r] = __shfl(linv, quad * 4 + r);
#pragma unroll
    for (int r = 0; r < 4; ++r) {
      size_t row = (size_t)(b * SEQL + qbase + qf * 16 + quad * 4 + r) * DM + h * DK;
#pragma unroll
      for (int df = 0; df < 4; ++df)
        O[row + df * 16 + c] = (bf16)(Oc[qf][df][r] * lr[r]);
    }
  }
}

// ---------------- launch ----------------
extern "C" void kernel_launch(void* const* d_in, const int* in_sizes, int n_in,
                              void* d_out, int out_size, void* d_ws, size_t ws_size,
                              hipStream_t stream) {
  const float* x   = (const float*)d_in[0];
  const int*   pad = (const int*)d_in[1];
  const float* Wq  = (const float*)d_in[2];
  const float* bq  = (const float*)d_in[3];
  const float* Wk  = (const float*)d_in[4];
  const float* bk  = (const float*)d_in[5];
  const float* Wv  = (const float*)d_in[6];
  const float* bv  = (const float*)d_in[7];
  const float* Wo  = (const float*)d_in[8];
  const float* bo  = (const float*)d_in[9];
  float* out = (float*)d_out;

  const size_t SZ_X = (size_t)NTOK * DM * 2;  // 16 MB
  const size_t SZ_W = (size_t)DM * DM * 2;    // 2 MB
  char* ws = (char*)d_ws;
  bf16* Xb  = (bf16*)ws;  ws += SZ_X;
  bf16* Wqb = (bf16*)ws;  ws += SZ_W;
  bf16* Wkb = (bf16*)ws;  ws += SZ_W;
  bf16* Wvb = (bf16*)ws;  ws += SZ_W;
  bf16* Wob = (bf16*)ws;  ws += SZ_W;
  bf16* Qb  = (bf16*)ws;  ws += SZ_X;
  bf16* Kb  = (bf16*)ws;  ws += SZ_X;
  bf16* Vtb = (bf16*)ws;  ws += SZ_X;   // [B,H,dk,S]
  bf16* Ob  = (bf16*)ws;  ws += SZ_X;

  cvt_x_kernel<<<4096, 256, 0, stream>>>(x, Xb);
  cvt_w_kernel<<<dim3(512, 4), 256, 0, stream>>>(Wq, Wk, Wv, Wo, Wqb, Wkb, Wvb, Wob);
  qkv_gemm<<<dim3(8, 64, 3), 256, 0, stream>>>(Xb, Wqb, Wkb, Wvb, bq, bk, bv, Qb, Kb, Vtb);
  attn_kernel<<<dim3(16, 16, 4), 256, 0, stream>>>(Qb, Kb, Vtb, pad, Ob);
  out_gemm<<<dim3(8, 64), 256, 0, stream>>>(Ob, Wob, bo, out);
}

// Round 3
// 387.507 us; speedup vs baseline: 1.4684x; 1.2893x over previous
//
#include <hip/hip_runtime.h>
#include <stdint.h>
#include <stddef.h>

// DecoderMHA: x[4,2048,1024] fp32 -> out fp32 [4,2048,1024]
// cvt(fused) -> QKV gemm (V transposed) -> no-max pipelined flash attn -> out proj.

typedef __bf16 bf16;
typedef __bf16 bf16x8 __attribute__((ext_vector_type(8)));
typedef __bf16 bf16x4 __attribute__((ext_vector_type(4)));
typedef float f32x4 __attribute__((ext_vector_type(4)));

#define DM   1024
#define NH   16
#define DK   64
#define BSZ  4
#define SEQL 2048
#define NTOK 8192   // BSZ*SEQL
#define NEGB -3.0e38f

__device__ __forceinline__ void async16(const bf16* g, bf16* l) {
  __builtin_amdgcn_global_load_lds(
      (__attribute__((address_space(1))) void*)g,
      (__attribute__((address_space(3))) void*)l, 16, 0, 0);
}

// ---------------- fused converts: x->bf16, W*4->bf16, pad->float bias ----------
__global__ __launch_bounds__(256) void cvt_all(
    const float* __restrict__ x,
    const float* __restrict__ w0, const float* __restrict__ w1,
    const float* __restrict__ w2, const float* __restrict__ w3,
    const int* __restrict__ pad,
    bf16* __restrict__ xd,
    bf16* __restrict__ d0, bf16* __restrict__ d1,
    bf16* __restrict__ d2, bf16* __restrict__ d3,
    float* __restrict__ padf) {
  int blk = blockIdx.x;
  if (blk >= 6144) {  // pad bias: 4 blocks x 2048 entries
    int i = (blk - 6144) * 2048 + threadIdx.x * 8;
    int4 p0 = *(const int4*)(pad + i);
    int4 p1 = *(const int4*)(pad + i + 4);
    float4 o0 = {p0.x ? NEGB : 0.f, p0.y ? NEGB : 0.f, p0.z ? NEGB : 0.f, p0.w ? NEGB : 0.f};
    float4 o1 = {p1.x ? NEGB : 0.f, p1.y ? NEGB : 0.f, p1.z ? NEGB : 0.f, p1.w ? NEGB : 0.f};
    *(float4*)(padf + i) = o0;
    *(float4*)(padf + i + 4) = o1;
    return;
  }
  const float* s; bf16* d; int i;
  if (blk < 4096) { s = x; d = xd; i = blk * 2048 + threadIdx.x * 8; }
  else {
    int m = (blk - 4096) >> 9, bi = (blk - 4096) & 511;
    switch (m) {
      case 0:  s = w0; d = d0; break;
      case 1:  s = w1; d = d1; break;
      case 2:  s = w2; d = d2; break;
      default: s = w3; d = d3; break;
    }
    i = bi * 2048 + threadIdx.x * 8;
  }
  float4 v0 = *(const float4*)(s + i);
  float4 v1 = *(const float4*)(s + i + 4);
  bf16x8 o = {(bf16)v0.x, (bf16)v0.y, (bf16)v0.z, (bf16)v0.w,
              (bf16)v1.x, (bf16)v1.y, (bf16)v1.z, (bf16)v1.w};
  *(bf16x8*)(d + i) = o;
}

// ---------------- 128x128 bf16 GEMM body (C = A @ W^T + bias) ----------------
// OUT_MODE 0: bf16 out head-split [B,H,S,dk]; 1: fp32 flat [M,1024]; 2: bf16 [B,H,dk,S]
template <int OUT_MODE>
__device__ __forceinline__ void gemm128(const bf16* __restrict__ A,
                                        const bf16* __restrict__ W,
                                        const float* __restrict__ bias,
                                        void* __restrict__ outp) {
  __shared__ bf16 As[128 * 32];
  __shared__ bf16 Bs[128 * 32];
  const int tid  = threadIdx.x;
  const int lane = tid & 63;
  const int wv   = tid >> 6;
  const int wm   = (wv & 1) * 64;
  const int wn   = (wv >> 1) * 64;
  const int c    = lane & 15;
  const int quad = lane >> 4;
  const int bm   = blockIdx.y * 128;
  const int bn   = blockIdx.x * 128;

  f32x4 acc[4][4] = {};

  for (int k0 = 0; k0 < DM; k0 += 32) {
    __syncthreads();
#pragma unroll
    for (int j = 0; j < 2; ++j) {
      int i = j * 256 + tid;
      async16(A + (size_t)(bm + (i >> 2)) * DM + k0 + (i & 3) * 8, As + i * 8);
      async16(W + (size_t)(bn + (i >> 2)) * DM + k0 + (i & 3) * 8, Bs + i * 8);
    }
    __syncthreads();
    bf16x8 af[4], bg[4];
#pragma unroll
    for (int mi = 0; mi < 4; ++mi)
      af[mi] = *(const bf16x8*)&As[(wm + mi * 16 + c) * 32 + quad * 8];
#pragma unroll
    for (int ni = 0; ni < 4; ++ni)
      bg[ni] = *(const bf16x8*)&Bs[(wn + ni * 16 + c) * 32 + quad * 8];
#pragma unroll
    for (int mi = 0; mi < 4; ++mi)
#pragma unroll
      for (int ni = 0; ni < 4; ++ni)
        acc[mi][ni] = __builtin_amdgcn_mfma_f32_16x16x32_bf16(af[mi], bg[ni],
                                                              acc[mi][ni], 0, 0, 0);
  }

  float bias_r[4];
#pragma unroll
  for (int ni = 0; ni < 4; ++ni) bias_r[ni] = bias[bn + wn + ni * 16 + c];

  if (OUT_MODE == 2) {
#pragma unroll
    for (int mi = 0; mi < 4; ++mi) {
      int base = bm + wm + mi * 16 + quad * 4;
      int bb = base >> 11, s0 = base & 2047;
#pragma unroll
      for (int ni = 0; ni < 4; ++ni) {
        int n_g = bn + wn + ni * 16 + c;
        int hh = n_g >> 6, dd = n_g & 63;
        bf16x4 pv = {(bf16)(acc[mi][ni][0] + bias_r[ni]),
                     (bf16)(acc[mi][ni][1] + bias_r[ni]),
                     (bf16)(acc[mi][ni][2] + bias_r[ni]),
                     (bf16)(acc[mi][ni][3] + bias_r[ni])};
        *(bf16x4*)&((bf16*)outp)[(((size_t)(bb * NH + hh)) * DK + dd) * SEQL + s0] = pv;
      }
    }
    return;
  }

#pragma unroll
  for (int mi = 0; mi < 4; ++mi) {
#pragma unroll
    for (int reg = 0; reg < 4; ++reg) {
      int m_g = bm + wm + mi * 16 + quad * 4 + reg;
#pragma unroll
      for (int ni = 0; ni < 4; ++ni) {
        int n_g = bn + wn + ni * 16 + c;
        float v = acc[mi][ni][reg] + bias_r[ni];
        if (OUT_MODE == 0) {
          int b = m_g >> 11, s = m_g & 2047;
          int h = n_g >> 6, d = n_g & 63;
          ((bf16*)outp)[(((size_t)(b * NH + h) * SEQL + s) << 6) + d] = (bf16)v;
        } else {
          ((float*)outp)[(size_t)m_g * DM + n_g] = v;
        }
      }
    }
  }
}

__global__ __launch_bounds__(256) void qkv_gemm(
    const bf16* __restrict__ X,
    const bf16* __restrict__ Wq, const bf16* __restrict__ Wk, const bf16* __restrict__ Wv,
    const float* __restrict__ bq, const float* __restrict__ bk, const float* __restrict__ bv,
    bf16* __restrict__ Q, bf16* __restrict__ K, bf16* __restrict__ Vt) {
  if (blockIdx.z == 0)      gemm128<0>(X, Wq, bq, Q);
  else if (blockIdx.z == 1) gemm128<0>(X, Wk, bk, K);
  else                      gemm128<2>(X, Wv, bv, Vt);
}

__global__ __launch_bounds__(256) void out_gemm(const bf16* __restrict__ A,
                                                const bf16* __restrict__ W,
                                                const float* __restrict__ bias,
                                                float* __restrict__ out) {
  gemm128<1>(A, W, bias, out);
}

// ---------------- barrier-free, no-max, pipelined flash attention ----------------
// Block = 4 waves; wave wv owns 32 q-rows. S^T = K.Q^T (col=query, row=key).
// No running max: p = exp2(fma(s,sc,padbias)); l = plain per-lane sum, reduced at end.
// K/bias prefetched one tile ahead; V issued at tile top, used after softmax.
// XCD swizzle: all 16 q-blocks of one (b,h) on one XCD (4 MB K+V = L2 size).
#define PSTR 40

__global__ __launch_bounds__(256) void attn_kernel(
    const bf16* __restrict__ Q, const bf16* __restrict__ K,
    const bf16* __restrict__ Vt, const float* __restrict__ padf,
    bf16* __restrict__ O) {
  const int id = blockIdx.x;
  const int xcd = id & 7, j = id >> 3;
  const int bh = xcd + 8 * (j >> 4);      // 8 heads per XCD
  const int b = bh >> 4, h = bh & 15;
  const int qblk = 15 - (j & 15);          // big causal blocks first
  const int tid  = threadIdx.x;
  const int lane = tid & 63;
  const int wv   = tid >> 6;
  const int c    = lane & 15;
  const int quad = lane >> 4;
  const int qbase = qblk * 128 + wv * 32;

  __shared__ bf16 Plds_all[4][32 * PSTR];
  bf16* Plds = &Plds_all[wv][0];

  const bf16* Qh  = Q  + (size_t)bh * SEQL * DK;
  const bf16* Kh  = K  + (size_t)bh * SEQL * DK;
  const bf16* Vth = Vt + (size_t)bh * DK * SEQL;
  const float* pb = padf + b * SEQL;

  // Q fragments (B-operand): lane c = query, k = kh*32 + quad*8 + j
  bf16x8 Qf[2][2];
#pragma unroll
  for (int qf = 0; qf < 2; ++qf)
#pragma unroll
    for (int kh = 0; kh < 2; ++kh)
      Qf[qf][kh] = *(const bf16x8*)&Qh[(size_t)(qbase + qf * 16 + c) * DK + kh * 32 + quad * 8];

  float l_s[2] = {0.f, 0.f};
  f32x4 Oc[2][4] = {};
  const float sc = 0.1803368801111204f;  // log2(e) / sqrt(64)
  const int nkt = qbase / 32 + 1;

  // prefetch K + bias for tile 0
  bf16x8 Kc[2][2];
  float4 bc[2];
#pragma unroll
  for (int kf = 0; kf < 2; ++kf) {
#pragma unroll
    for (int kh = 0; kh < 2; ++kh)
      Kc[kf][kh] = *(const bf16x8*)&Kh[(size_t)(kf * 16 + c) * DK + kh * 32 + quad * 8];
    bc[kf] = *(const float4*)&pb[kf * 16 + quad * 4];
  }

  for (int kt = 0; kt < nkt; ++kt) {
    const int kb = kt * 32;

    // V for current tile (consumed after softmax, ~300 cyc later)
    bf16x8 Vc[4];
#pragma unroll
    for (int df = 0; df < 4; ++df)
      Vc[df] = *(const bf16x8*)&Vth[(size_t)(df * 16 + c) * SEQL + kb + quad * 8];

    // S^T = K.Q^T
    f32x4 st[2][2] = {};
#pragma unroll
    for (int kh = 0; kh < 2; ++kh)
#pragma unroll
      for (int kf = 0; kf < 2; ++kf)
#pragma unroll
        for (int qf = 0; qf < 2; ++qf)
          st[kf][qf] = __builtin_amdgcn_mfma_f32_16x16x32_bf16(Kc[kf][kh], Qf[qf][kh],
                                                               st[kf][qf], 0, 0, 0);

    // prefetch next K + bias (clamped: redundant re-load on last iter, always in-bounds)
    const int kb2 = (kb + 32 <= qbase) ? kb + 32 : kb;
    bf16x8 Kn[2][2];
    float4 bn[2];
#pragma unroll
    for (int kf = 0; kf < 2; ++kf) {
#pragma unroll
      for (int kh = 0; kh < 2; ++kh)
        Kn[kf][kh] = *(const bf16x8*)&Kh[(size_t)(kb2 + kf * 16 + c) * DK + kh * 32 + quad * 8];
      bn[kf] = *(const float4*)&pb[kb2 + kf * 16 + quad * 4];
    }

    // softmax without max-subtraction; masked keys -> exp2(-3e38) = 0
    const bool lastt = (kt == nkt - 1);
#pragma unroll
    for (int qf = 0; qf < 2; ++qf) {
      float p[8];
#pragma unroll
      for (int kf = 0; kf < 2; ++kf) {
        const float* bv4 = (const float*)&bc[kf];
#pragma unroll
        for (int r = 0; r < 4; ++r) {
          float e = __builtin_amdgcn_exp2f(__builtin_fmaf(st[kf][qf][r], sc, bv4[r]));
          if (lastt && (kf * 16 + quad * 4 + r > qf * 16 + c)) e = 0.f;
          p[kf * 4 + r] = e;
          l_s[qf] += e;
        }
      }
      bf16x4 pk0 = {(bf16)p[0], (bf16)p[1], (bf16)p[2], (bf16)p[3]};
      bf16x4 pk1 = {(bf16)p[4], (bf16)p[5], (bf16)p[6], (bf16)p[7]};
      *(bf16x4*)&Plds[(qf * 16 + c) * PSTR + quad * 4] = pk0;
      *(bf16x4*)&Plds[(qf * 16 + c) * PSTR + 16 + quad * 4] = pk1;
    }

    // O += P @ V
#pragma unroll
    for (int qf = 0; qf < 2; ++qf) {
      bf16x8 af = *(const bf16x8*)&Plds[(qf * 16 + c) * PSTR + quad * 8];
#pragma unroll
      for (int df = 0; df < 4; ++df)
        Oc[qf][df] = __builtin_amdgcn_mfma_f32_16x16x32_bf16(af, Vc[df], Oc[qf][df], 0, 0, 0);
    }

#pragma unroll
    for (int kf = 0; kf < 2; ++kf) {
#pragma unroll
      for (int kh = 0; kh < 2; ++kh) Kc[kf][kh] = Kn[kf][kh];
      bc[kf] = bn[kf];
    }
  }

  // epilogue: reduce l across quads, divide, store
#pragma unroll
  for (int qf = 0; qf < 2; ++qf) {
    float l = l_s[qf];
    l += __shfl_xor(l, 16);
    l += __shfl_xor(l, 32);
    float linv = (l > 0.f) ? 1.f / l : 0.f;
    float lr[4];
#pragma unroll
    for (int r = 0; r < 4; ++r) lr[r] = __shfl(linv, quad * 4 + r);
#pragma unroll
    for (int r = 0; r < 4; ++r) {
      size_t row = (size_t)(b * SEQL + qbase + qf * 16 + quad * 4 + r) * DM + h * DK;
#pragma unroll
      for (int df = 0; df < 4; ++df)
        O[row + df * 16 + c] = (bf16)(Oc[qf][df][r] * lr[r]);
    }
  }
}

// ---------------- launch ----------------
extern "C" void kernel_launch(void* const* d_in, const int* in_sizes, int n_in,
                              void* d_out, int out_size, void* d_ws, size_t ws_size,
                              hipStream_t stream) {
  const float* x   = (const float*)d_in[0];
  const int*   pad = (const int*)d_in[1];
  const float* Wq  = (const float*)d_in[2];
  const float* bq  = (const float*)d_in[3];
  const float* Wk  = (const float*)d_in[4];
  const float* bk  = (const float*)d_in[5];
  const float* Wv  = (const float*)d_in[6];
  const float* bv  = (const float*)d_in[7];
  const float* Wo  = (const float*)d_in[8];
  const float* bo  = (const float*)d_in[9];
  float* out = (float*)d_out;

  const size_t SZ_X = (size_t)NTOK * DM * 2;  // 16 MB
  const size_t SZ_W = (size_t)DM * DM * 2;    // 2 MB
  char* ws = (char*)d_ws;
  bf16* Xb  = (bf16*)ws;  ws += SZ_X;
  bf16* Wqb = (bf16*)ws;  ws += SZ_W;
  bf16* Wkb = (bf16*)ws;  ws += SZ_W;
  bf16* Wvb = (bf16*)ws;  ws += SZ_W;
  bf16* Wob = (bf16*)ws;  ws += SZ_W;
  bf16* Qb  = (bf16*)ws;  ws += SZ_X;
  bf16* Kb  = (bf16*)ws;  ws += SZ_X;
  bf16* Vtb = (bf16*)ws;  ws += SZ_X;   // [B,H,dk,S]
  bf16* Ob  = (bf16*)ws;  ws += SZ_X;
  float* padfb = (float*)ws; ws += (size_t)NTOK * 4;

  cvt_all<<<6148, 256, 0, stream>>>(x, Wq, Wk, Wv, Wo, pad,
                                    Xb, Wqb, Wkb, Wvb, Wob, padfb);
  qkv_gemm<<<dim3(8, 64, 3), 256, 0, stream>>>(Xb, Wqb, Wkb, Wvb, bq, bk, bv, Qb, Kb, Vtb);
  attn_kernel<<<1024, 256, 0, stream>>>(Qb, Kb, Vtb, padfb, Ob);
  out_gemm<<<dim3(8, 64), 256, 0, stream>>>(Ob, Wob, bo, out);
}

// Round 4
// 358.578 us; speedup vs baseline: 1.5869x; 1.0807x over previous
//
#include <hip/hip_runtime.h>
#include <stdint.h>
#include <stddef.h>

// DecoderMHA: x[4,2048,1024] fp32 -> out fp32 [4,2048,1024]
// cvt(fused) -> QKV gemm (V transposed) -> balanced per-wave no-max flash attn -> out proj.

typedef __bf16 bf16;
typedef __bf16 bf16x8 __attribute__((ext_vector_type(8)));
typedef __bf16 bf16x4 __attribute__((ext_vector_type(4)));
typedef float f32x4 __attribute__((ext_vector_type(4)));

#define DM   1024
#define NH   16
#define DK   64
#define BSZ  4
#define SEQL 2048
#define NTOK 8192   // BSZ*SEQL
#define NEGB -3.0e38f

__device__ __forceinline__ void async16(const bf16* g, bf16* l) {
  __builtin_amdgcn_global_load_lds(
      (__attribute__((address_space(1))) void*)g,
      (__attribute__((address_space(3))) void*)l, 16, 0, 0);
}

// ---------------- fused converts: x->bf16, W*4->bf16, pad->float bias ----------
__global__ __launch_bounds__(256) void cvt_all(
    const float* __restrict__ x,
    const float* __restrict__ w0, const float* __restrict__ w1,
    const float* __restrict__ w2, const float* __restrict__ w3,
    const int* __restrict__ pad,
    bf16* __restrict__ xd,
    bf16* __restrict__ d0, bf16* __restrict__ d1,
    bf16* __restrict__ d2, bf16* __restrict__ d3,
    float* __restrict__ padf) {
  int blk = blockIdx.x;
  if (blk >= 6144) {  // pad bias: 4 blocks x 2048 entries
    int i = (blk - 6144) * 2048 + threadIdx.x * 8;
    int4 p0 = *(const int4*)(pad + i);
    int4 p1 = *(const int4*)(pad + i + 4);
    float4 o0 = {p0.x ? NEGB : 0.f, p0.y ? NEGB : 0.f, p0.z ? NEGB : 0.f, p0.w ? NEGB : 0.f};
    float4 o1 = {p1.x ? NEGB : 0.f, p1.y ? NEGB : 0.f, p1.z ? NEGB : 0.f, p1.w ? NEGB : 0.f};
    *(float4*)(padf + i) = o0;
    *(float4*)(padf + i + 4) = o1;
    return;
  }
  const float* s; bf16* d; int i;
  if (blk < 4096) { s = x; d = xd; i = blk * 2048 + threadIdx.x * 8; }
  else {
    int m = (blk - 4096) >> 9, bi = (blk - 4096) & 511;
    switch (m) {
      case 0:  s = w0; d = d0; break;
      case 1:  s = w1; d = d1; break;
      case 2:  s = w2; d = d2; break;
      default: s = w3; d = d3; break;
    }
    i = bi * 2048 + threadIdx.x * 8;
  }
  float4 v0 = *(const float4*)(s + i);
  float4 v1 = *(const float4*)(s + i + 4);
  bf16x8 o = {(bf16)v0.x, (bf16)v0.y, (bf16)v0.z, (bf16)v0.w,
              (bf16)v1.x, (bf16)v1.y, (bf16)v1.z, (bf16)v1.w};
  *(bf16x8*)(d + i) = o;
}

// ---------------- 128x128 bf16 GEMM body (C = A @ W^T + bias) ----------------
// OUT_MODE 0: bf16 out head-split [B,H,S,dk]; 1: fp32 flat [M,1024]; 2: bf16 [B,H,dk,S]
template <int OUT_MODE>
__device__ __forceinline__ void gemm128(const bf16* __restrict__ A,
                                        const bf16* __restrict__ W,
                                        const float* __restrict__ bias,
                                        void* __restrict__ outp) {
  __shared__ bf16 As[128 * 32];
  __shared__ bf16 Bs[128 * 32];
  const int tid  = threadIdx.x;
  const int lane = tid & 63;
  const int wv   = tid >> 6;
  const int wm   = (wv & 1) * 64;
  const int wn   = (wv >> 1) * 64;
  const int c    = lane & 15;
  const int quad = lane >> 4;
  const int bm   = blockIdx.y * 128;
  const int bn   = blockIdx.x * 128;

  f32x4 acc[4][4] = {};

  for (int k0 = 0; k0 < DM; k0 += 32) {
    __syncthreads();
#pragma unroll
    for (int j = 0; j < 2; ++j) {
      int i = j * 256 + tid;
      async16(A + (size_t)(bm + (i >> 2)) * DM + k0 + (i & 3) * 8, As + i * 8);
      async16(W + (size_t)(bn + (i >> 2)) * DM + k0 + (i & 3) * 8, Bs + i * 8);
    }
    __syncthreads();
    bf16x8 af[4], bg[4];
#pragma unroll
    for (int mi = 0; mi < 4; ++mi)
      af[mi] = *(const bf16x8*)&As[(wm + mi * 16 + c) * 32 + quad * 8];
#pragma unroll
    for (int ni = 0; ni < 4; ++ni)
      bg[ni] = *(const bf16x8*)&Bs[(wn + ni * 16 + c) * 32 + quad * 8];
#pragma unroll
    for (int mi = 0; mi < 4; ++mi)
#pragma unroll
      for (int ni = 0; ni < 4; ++ni)
        acc[mi][ni] = __builtin_amdgcn_mfma_f32_16x16x32_bf16(af[mi], bg[ni],
                                                              acc[mi][ni], 0, 0, 0);
  }

  float bias_r[4];
#pragma unroll
  for (int ni = 0; ni < 4; ++ni) bias_r[ni] = bias[bn + wn + ni * 16 + c];

  if (OUT_MODE == 2) {
#pragma unroll
    for (int mi = 0; mi < 4; ++mi) {
      int base = bm + wm + mi * 16 + quad * 4;
      int bb = base >> 11, s0 = base & 2047;
#pragma unroll
      for (int ni = 0; ni < 4; ++ni) {
        int n_g = bn + wn + ni * 16 + c;
        int hh = n_g >> 6, dd = n_g & 63;
        bf16x4 pv = {(bf16)(acc[mi][ni][0] + bias_r[ni]),
                     (bf16)(acc[mi][ni][1] + bias_r[ni]),
                     (bf16)(acc[mi][ni][2] + bias_r[ni]),
                     (bf16)(acc[mi][ni][3] + bias_r[ni])};
        *(bf16x4*)&((bf16*)outp)[(((size_t)(bb * NH + hh)) * DK + dd) * SEQL + s0] = pv;
      }
    }
    return;
  }

#pragma unroll
  for (int mi = 0; mi < 4; ++mi) {
#pragma unroll
    for (int reg = 0; reg < 4; ++reg) {
      int m_g = bm + wm + mi * 16 + quad * 4 + reg;
#pragma unroll
      for (int ni = 0; ni < 4; ++ni) {
        int n_g = bn + wn + ni * 16 + c;
        float v = acc[mi][ni][reg] + bias_r[ni];
        if (OUT_MODE == 0) {
          int b = m_g >> 11, s = m_g & 2047;
          int h = n_g >> 6, d = n_g & 63;
          ((bf16*)outp)[(((size_t)(b * NH + h) * SEQL + s) << 6) + d] = (bf16)v;
        } else {
          ((float*)outp)[(size_t)m_g * DM + n_g] = v;
        }
      }
    }
  }
}

__global__ __launch_bounds__(256) void qkv_gemm(
    const bf16* __restrict__ X,
    const bf16* __restrict__ Wq, const bf16* __restrict__ Wk, const bf16* __restrict__ Wv,
    const float* __restrict__ bq, const float* __restrict__ bk, const float* __restrict__ bv,
    bf16* __restrict__ Q, bf16* __restrict__ K, bf16* __restrict__ Vt) {
  if (blockIdx.z == 0)      gemm128<0>(X, Wq, bq, Q);
  else if (blockIdx.z == 1) gemm128<0>(X, Wk, bk, K);
  else                      gemm128<2>(X, Wv, bv, Vt);
}

__global__ __launch_bounds__(256) void out_gemm(const bf16* __restrict__ A,
                                                const bf16* __restrict__ W,
                                                const float* __restrict__ bias,
                                                float* __restrict__ out) {
  gemm128<1>(A, W, bias, out);
}

// ---------------- balanced per-wave no-max flash attention ----------------
// One work item = (bh, 32-row q-tile). 4096 items, one per wave, 1024 blocks.
// Block j's waves take q-tiles {2j, 63-2j, 2j+1, 62-2j} -> every block does
// exactly 130 key-tiles: zero tail imbalance. XCD swizzle: bh = bh_hi*8 + (blk&7),
// so one (b,h)'s K/V (512 KB) stays in one XCD's L2.
#define PSTR 40

__global__ __launch_bounds__(256) void attn_kernel(
    const bf16* __restrict__ Q, const bf16* __restrict__ K,
    const bf16* __restrict__ Vt, const float* __restrict__ padf,
    bf16* __restrict__ O) {
  const int B = blockIdx.x;
  const int xcd = B & 7;
  const int j = (B >> 3) & 15;      // 16 blocks per bh
  const int bh = ((B >> 7) << 3) + xcd;
  const int b = bh >> 4, h = bh & 15;
  const int tid  = threadIdx.x;
  const int lane = tid & 63;
  const int wv   = tid >> 6;
  const int c    = lane & 15;
  const int quad = lane >> 4;
  const int p = j * 2 + (wv >> 1);             // 0..31
  const int qt = (wv & 1) ? 63 - p : p;        // paired for balance
  const int qbase = qt * 32;

  __shared__ bf16 Plds_all[4][32 * PSTR];
  bf16* Plds = &Plds_all[wv][0];

  const bf16* Qh  = Q  + (size_t)bh * SEQL * DK;
  const bf16* Kh  = K  + (size_t)bh * SEQL * DK;
  const bf16* Vth = Vt + (size_t)bh * DK * SEQL;
  const float* pb = padf + b * SEQL;

  // Q fragments (B-operand): lane c = query, k = kh*32 + quad*8 + jj
  bf16x8 Qf[2][2];
#pragma unroll
  for (int qf = 0; qf < 2; ++qf)
#pragma unroll
    for (int kh = 0; kh < 2; ++kh)
      Qf[qf][kh] = *(const bf16x8*)&Qh[(size_t)(qbase + qf * 16 + c) * DK + kh * 32 + quad * 8];

  float l_s[2] = {0.f, 0.f};
  f32x4 Oc[2][4] = {};
  const float sc = 0.1803368801111204f;  // log2(e) / sqrt(64)
  const int nkt = qt + 1;

  // prefetch K + bias for tile 0
  bf16x8 Kc[2][2];
  float4 bc[2];
#pragma unroll
  for (int kf = 0; kf < 2; ++kf) {
#pragma unroll
    for (int kh = 0; kh < 2; ++kh)
      Kc[kf][kh] = *(const bf16x8*)&Kh[(size_t)(kf * 16 + c) * DK + kh * 32 + quad * 8];
    bc[kf] = *(const float4*)&pb[kf * 16 + quad * 4];
  }

  for (int kt = 0; kt < nkt; ++kt) {
    const int kb = kt * 32;

    // V for current tile (consumed after softmax)
    bf16x8 Vc[4];
#pragma unroll
    for (int df = 0; df < 4; ++df)
      Vc[df] = *(const bf16x8*)&Vth[(size_t)(df * 16 + c) * SEQL + kb + quad * 8];

    // S^T = K.Q^T  (col=query, row=key)
    f32x4 st[2][2] = {};
#pragma unroll
    for (int kh = 0; kh < 2; ++kh)
#pragma unroll
      for (int kf = 0; kf < 2; ++kf)
#pragma unroll
        for (int qf = 0; qf < 2; ++qf)
          st[kf][qf] = __builtin_amdgcn_mfma_f32_16x16x32_bf16(Kc[kf][kh], Qf[qf][kh],
                                                               st[kf][qf], 0, 0, 0);

    // prefetch next K + bias (clamped redundant re-load on last iter)
    const int kb2 = (kb + 32 <= qbase) ? kb + 32 : kb;
    bf16x8 Kn[2][2];
    float4 bn[2];
#pragma unroll
    for (int kf = 0; kf < 2; ++kf) {
#pragma unroll
      for (int kh = 0; kh < 2; ++kh)
        Kn[kf][kh] = *(const bf16x8*)&Kh[(size_t)(kb2 + kf * 16 + c) * DK + kh * 32 + quad * 8];
      bn[kf] = *(const float4*)&pb[kb2 + kf * 16 + quad * 4];
    }

    // softmax without max-subtraction; masked keys -> exp2(-3e38) = 0
    const bool lastt = (kt == nkt - 1);
#pragma unroll
    for (int qf = 0; qf < 2; ++qf) {
      float p8[8];
#pragma unroll
      for (int kf = 0; kf < 2; ++kf) {
        const float* bv4 = (const float*)&bc[kf];
#pragma unroll
        for (int r = 0; r < 4; ++r) {
          float e = __builtin_amdgcn_exp2f(__builtin_fmaf(st[kf][qf][r], sc, bv4[r]));
          if (lastt && (kf * 16 + quad * 4 + r > qf * 16 + c)) e = 0.f;
          p8[kf * 4 + r] = e;
          l_s[qf] += e;
        }
      }
      bf16x4 pk0 = {(bf16)p8[0], (bf16)p8[1], (bf16)p8[2], (bf16)p8[3]};
      bf16x4 pk1 = {(bf16)p8[4], (bf16)p8[5], (bf16)p8[6], (bf16)p8[7]};
      *(bf16x4*)&Plds[(qf * 16 + c) * PSTR + quad * 4] = pk0;
      *(bf16x4*)&Plds[(qf * 16 + c) * PSTR + 16 + quad * 4] = pk1;
    }

    // O += P @ V
#pragma unroll
    for (int qf = 0; qf < 2; ++qf) {
      bf16x8 af = *(const bf16x8*)&Plds[(qf * 16 + c) * PSTR + quad * 8];
#pragma unroll
      for (int df = 0; df < 4; ++df)
        Oc[qf][df] = __builtin_amdgcn_mfma_f32_16x16x32_bf16(af, Vc[df], Oc[qf][df], 0, 0, 0);
    }

#pragma unroll
    for (int kf = 0; kf < 2; ++kf) {
#pragma unroll
      for (int kh = 0; kh < 2; ++kh) Kc[kf][kh] = Kn[kf][kh];
      bc[kf] = bn[kf];
    }
  }

  // epilogue: reduce l across quads, divide, store
#pragma unroll
  for (int qf = 0; qf < 2; ++qf) {
    float l = l_s[qf];
    l += __shfl_xor(l, 16);
    l += __shfl_xor(l, 32);
    float linv = (l > 0.f) ? 1.f / l : 0.f;
    float lr[4];
#pragma unroll
    for (int r = 0; r < 4; ++r) lr[r] = __shfl(linv, quad * 4 + r);
#pragma unroll
    for (int r = 0; r < 4; ++r) {
      size_t row = (size_t)(b * SEQL + qbase + qf * 16 + quad * 4 + r) * DM + h * DK;
#pragma unroll
      for (int df = 0; df < 4; ++df)
        O[row + df * 16 + c] = (bf16)(Oc[qf][df][r] * lr[r]);
    }
  }
}

// ---------------- launch ----------------
extern "C" void kernel_launch(void* const* d_in, const int* in_sizes, int n_in,
                              void* d_out, int out_size, void* d_ws, size_t ws_size,
                              hipStream_t stream) {
  const float* x   = (const float*)d_in[0];
  const int*   pad = (const int*)d_in[1];
  const float* Wq  = (const float*)d_in[2];
  const float* bq  = (const float*)d_in[3];
  const float* Wk  = (const float*)d_in[4];
  const float* bk  = (const float*)d_in[5];
  const float* Wv  = (const float*)d_in[6];
  const float* bv  = (const float*)d_in[7];
  const float* Wo  = (const float*)d_in[8];
  const float* bo  = (const float*)d_in[9];
  float* out = (float*)d_out;

  const size_t SZ_X = (size_t)NTOK * DM * 2;  // 16 MB
  const size_t SZ_W = (size_t)DM * DM * 2;    // 2 MB
  char* ws = (char*)d_ws;
  bf16* Xb  = (bf16*)ws;  ws += SZ_X;
  bf16* Wqb = (bf16*)ws;  ws += SZ_W;
  bf16* Wkb = (bf16*)ws;  ws += SZ_W;
  bf16* Wvb = (bf16*)ws;  ws += SZ_W;
  bf16* Wob = (bf16*)ws;  ws += SZ_W;
  bf16* Qb  = (bf16*)ws;  ws += SZ_X;
  bf16* Kb  = (bf16*)ws;  ws += SZ_X;
  bf16* Vtb = (bf16*)ws;  ws += SZ_X;   // [B,H,dk,S]
  bf16* Ob  = (bf16*)ws;  ws += SZ_X;
  float* padfb = (float*)ws; ws += (size_t)NTOK * 4;

  cvt_all<<<6148, 256, 0, stream>>>(x, Wq, Wk, Wv, Wo, pad,
                                    Xb, Wqb, Wkb, Wvb, Wob, padfb);
  qkv_gemm<<<dim3(8, 64, 3), 256, 0, stream>>>(Xb, Wqb, Wkb, Wvb, bq, bk, bv, Qb, Kb, Vtb);
  attn_kernel<<<1024, 256, 0, stream>>>(Qb, Kb, Vtb, padfb, Ob);
  out_gemm<<<dim3(8, 64), 256, 0, stream>>>(Ob, Wob, bo, out);
}